// Round 15
// baseline (114.385 us; speedup 1.0000x reference)
//
#include <hip/hip_runtime.h>
#include <hip/hip_bf16.h>

typedef unsigned short u16;
typedef __attribute__((ext_vector_type(4))) short short4v;
typedef __attribute__((ext_vector_type(8))) short short8v;
typedef __attribute__((ext_vector_type(4))) float float4v;

#define NF 2
#define NLOC 4096
#define NALL 8192
#define NNEI_ 138
#define ATOMS_PER_BLOCK 4
#define X2STR 76   // u16 stride of X2 rows: 152 B -> b64-aligned, ~2-way banks both sides

// Compiler-only ordering fence (strict-aliasing write->read on LDS).
#define COMPILER_LDS_FENCE() asm volatile("" ::: "memory")

__device__ __forceinline__ float fast_tanh(float a) {
#if __has_builtin(__builtin_amdgcn_exp2f) && __has_builtin(__builtin_amdgcn_rcpf)
    float t = __builtin_amdgcn_exp2f(a * 2.885390081777927f);  // exp(2a)
    return 1.0f - 2.0f * __builtin_amdgcn_rcpf(t + 1.0f);
#else
    float t = exp2f(a * 2.885390081777927f);
    return 1.0f - 2.0f / (t + 1.0f);
#endif
}

__device__ __forceinline__ u16 f2bf(float x) {
    __hip_bfloat16 h = __float2bfloat16(x);
    return *reinterpret_cast<u16*>(&h);
}

__device__ __forceinline__ float bf2f(u16 b) {
    union { unsigned int u; float f; } c;
    c.u = ((unsigned int)b) << 16;
    return c.f;
}

// Pack weights into MFMA B-fragment order (bf16), zero-padded, plus a
// fast_tanh(b2) f32 table (for the pad-row correction in the main kernel).
// ws layout (bf16 elems): [0,4096) B1 pack; [4096,18432) B2 pack;
//                         byte 36864+: f32 tanhB2[2][112].
__global__ void prep_weights(const float* __restrict__ w1, const float* __restrict__ w2,
                             const float* __restrict__ b2,
                             __hip_bfloat16* __restrict__ wsbf) {
    int i = threadIdx.x + blockIdx.x * blockDim.x;
    if (i < 4096) {
        int e = i & 7, lane = (i >> 3) & 63, nt = (i >> 9) & 3, t = i >> 11;
        int k = (lane >> 4) * 8 + e, j = nt * 16 + (lane & 15);
        float v = (k < 25 && j < 50) ? w1[t * 1250 + k * 50 + j] : 0.0f;
        wsbf[i] = __float2bfloat16(v);
    } else if (i < 4096 + 14336) {
        int j2 = i - 4096;
        int e = j2 & 7, lane = (j2 >> 3) & 63;
        int q = j2 >> 9;
        int nt = q % 7, kt = (q / 7) & 1, t = q / 14;
        int k = kt * 32 + (lane >> 4) * 8 + e, j = nt * 16 + (lane & 15);
        float v = (k < 50 && j < 100) ? w2[t * 5000 + k * 100 + j] : 0.0f;
        wsbf[4096 + j2] = __float2bfloat16(v);
    }
    if (i < 224) {
        int t = i / 112, col = i % 112;
        float v = (col < 100) ? fast_tanh(b2[t * 100 + col]) : 0.0f;
        reinterpret_cast<float*>(reinterpret_cast<char*>(wsbf) + 36864)[i] = v;
    }
}

// Block = ATOMS_PER_BLOCK atoms, processed sequentially.
// Per atom, ROLE r = (wave + ai) & 3 decides the row group:
//   role 0: rows 0-47   = type0 neighbors 0-45 (+2 pad), 3 M-tiles (HEAVY)
//   role r: rows 48+32(r-1).. = type1 neighbors (+pad on role 3), 2 M-tiles
// Rotating role per atom equalizes per-wave (hence per-SIMD) VALU work:
// without rotation, wave 0 (pinned to SIMD 0) carries ~1.6x the tanh work of
// waves 1-3 and SIMD 0 saturates while SIMDs 1-3 starve at the merge barrier.
__global__ __launch_bounds__(256, 3) void descr_mfma(
    const float* __restrict__ coord, const int* __restrict__ atype,
    const int* __restrict__ nlist, const float* __restrict__ mean,
    const float* __restrict__ stddev,
    const float* __restrict__ w0, const float* __restrict__ b0,
    const float* __restrict__ b1, const float* __restrict__ b2,
    const __hip_bfloat16* __restrict__ B1f, const __hip_bfloat16* __restrict__ B2f,
    const float* __restrict__ TB2,
    float* __restrict__ out_res, float* __restrict__ out_sw)
{
    // X: layer-0 activations, row-major 64B rows, 16B-slot swizzle
    //    slot(row, sl) = sl ^ (row&3) ^ ((row>>2)&3)
    __shared__ __align__(16) u16 X[144 * 32];               // 9216 B
    // X2: per-(physical-)wave current-tile x2, ROW-major [16 rows][X2STR]
    __shared__ __align__(16) u16 X2[4 * 16 * X2STR];        // 9728 B
    __shared__ __align__(16) u16 B2L[2 * 7168];             // 28672 B, full B2 pack (both types)
    __shared__ float psum[2][4][112];                       // 3584 B (ping-pong by atom parity)
    __shared__ float s2w[2][4][64];                         // 2048 B

    const int tid = threadIdx.x, wave = tid >> 6, lane = tid & 63;
    const int m = lane & 15, qt = lane >> 4;
    u16* const X2w = X2 + wave * (16 * X2STR);

    // ---------------- stage full B2 pack into LDS once per block ----------------
    {
        const uint4* src = reinterpret_cast<const uint4*>(B2f);   // 28672 B = 1792 uint4
        uint4* dst = reinterpret_cast<uint4*>(B2L);
#pragma unroll
        for (int i = 0; i < 7; ++i) {
            int idx = tid + i * 256;
            dst[idx] = src[idx];
        }
    }
    // pre-zero X's constant pad words (logical slot 3, words 1-3 = kk 13..15)
    for (int r = tid; r < 144; r += 256) {
        const int sx = (r & 3) ^ ((r >> 2) & 3);
        char* p = reinterpret_cast<char*>(X) + r * 64 + ((3 ^ sx) << 4);
        *reinterpret_cast<unsigned int*>(p + 4) = 0u;
        *reinterpret_cast<unsigned int*>(p + 8) = 0u;
        *reinterpret_cast<unsigned int*>(p + 12) = 0u;
    }
    __syncthreads();

#pragma unroll 1
    for (int ai = 0; ai < ATOMS_PER_BLOCK; ++ai) {
        const int b = blockIdx.x * ATOMS_PER_BLOCK + ai;
        const int f = b >> 12, il = b & 4095;
        const int par = ai & 1;

        // -------- role rotation: balance heavy role 0 across waves/SIMDs --------
        const int role = (wave + ai) & 3;
        const int t = role ? 1 : 0;
        const int row_base = role ? (48 + 32 * (role - 1)) : 0;
        const int n_rows = role ? 32 : 48;
        const int mtiles = role ? 2 : 3;
        const int vlimit = (role == 0) ? 46 : ((role == 3) ? 28 : 32);
        const float npad = (role == 0) ? 2.0f : ((role == 3) ? 4.0f : 0.0f);

        // per-role constants (L1-hot reloads, ~16 small loads/atom)
        const float* w0t = w0 + t * 25;
        const float* b0t = b0 + t * 25;
        float b1v[4], b2v[7], corr[7];
        int rofb[4];
#pragma unroll
        for (int nt = 0; nt < 4; ++nt) {
            int col = nt * 16 + m;
            b1v[nt] = (col < 50) ? b1[t * 50 + col] : 0.0f;
            int cm = (col < 25) ? col : ((col < 50) ? (col - 25) : 0);
            rofb[nt] = ((cm >> 3) << 4) | ((cm & 7) * 2);
        }
#pragma unroll
        for (int nt = 0; nt < 7; ++nt) {
            int col = nt * 16 + m;
            b2v[nt] = (col < 100) ? b2[t * 100 + col] : 0.0f;
            corr[nt] = npad * TB2[t * 112 + col];   // == npad * fast_tanh(b2v[nt])
        }
        short8v B1g[4];
#pragma unroll
        for (int nt = 0; nt < 4; ++nt)
            B1g[nt] = *(const short8v*)(B1f + ((t * 4 + nt) * 64 + lane) * 8);
        const u16* const B2Ll = B2L + t * 7168 + lane * 8;

        const int aty = atype[f * NALL + il];
        const float cx = coord[(f * NALL + il) * 3 + 0];
        const float cy = coord[(f * NALL + il) * 3 + 1];
        const float cz = coord[(f * NALL + il) * 3 + 2];

        // ---------------- phase A: s, sw, X staging (role-private rows) ----------------
        {
            float s = 0.0f;
            if (lane < vlimit) {
                const int n = role ? (row_base + lane - 2) : lane;   // neighbor slot 0..137
                int jn = nlist[b * NNEI_ + n];
                float sw = 0.0f, env = 0.0f;
                if (jn >= 0) {
                    float dx = coord[(f * NALL + jn) * 3 + 0] - cx;
                    float dy = coord[(f * NALL + jn) * 3 + 1] - cy;
                    float dz = coord[(f * NALL + jn) * 3 + 2] - cz;
                    float len = sqrtf(dx * dx + dy * dy + dz * dz);
                    float uu = (len - 0.5f) * (1.0f / 5.5f);
                    float vv = uu * uu * uu * (uu * (-6.0f * uu + 15.0f) - 10.0f) + 1.0f;
                    sw = (len <= 0.5f) ? 1.0f : ((len >= 6.0f) ? 0.0f : vv);
                    env = sw / len;
                }
                out_sw[b * NNEI_ + n] = sw;
                s = (env - mean[aty * NNEI_ + n]) / stddev[aty * NNEI_ + n];
            }
            if (role == 0) {
                // 48 rows: uint4 path, lanes 0-47
                const int row = lane;
                if (lane < n_rows) {
                    unsigned int xp[16];
#pragma unroll
                    for (int kk = 0; kk < 13; ++kk) {
                        float v0 = fast_tanh(s * w0t[2 * kk] + b0t[2 * kk]);
                        float v1 = (2 * kk + 1 < 25) ? fast_tanh(s * w0t[2 * kk + 1] + b0t[2 * kk + 1]) : 0.0f;
                        xp[kk] = (unsigned int)f2bf(v0) | ((unsigned int)f2bf(v1) << 16);
                    }
                    xp[13] = 0; xp[14] = 0; xp[15] = 0;
#pragma unroll
                    for (int sl = 0; sl < 4; ++sl) {
                        int slot = sl ^ (row & 3) ^ ((row >> 2) & 3);
                        uint4 v = make_uint4(xp[4 * sl], xp[4 * sl + 1], xp[4 * sl + 2], xp[4 * sl + 3]);
                        *reinterpret_cast<uint4*>(reinterpret_cast<char*>(X) + row * 64 + slot * 16) = v;
                    }
                }
            } else {
                // 32 rows over 64 lanes: lane pair (l, l+32) shares row l, splits 13 pairs 7/6.
                const float sr = __shfl(s, lane & 31);
                const int row = row_base + (lane & 31);
                const int sx = (row & 3) ^ ((row >> 2) & 3);
                char* const Xrow = reinterpret_cast<char*>(X) + row * 64;
                const int kb = (lane >> 5) * 7;
#pragma unroll
                for (int i = 0; i < 7; ++i) {
                    const int kk = kb + i;
                    if (kk < 13) {
                        float v0 = fast_tanh(sr * w0t[2 * kk] + b0t[2 * kk]);
                        float v1 = (2 * kk + 1 < 25) ? fast_tanh(sr * w0t[2 * kk + 1] + b0t[2 * kk + 1]) : 0.0f;
                        unsigned int pv = (unsigned int)f2bf(v0) | ((unsigned int)f2bf(v1) << 16);
                        *reinterpret_cast<unsigned int*>(
                            Xrow + ((((kk >> 2) ^ sx) << 4) | ((kk & 3) << 2))) = pv;
                    }
                }
            }
        }
        // order phase-A X stores before a1/residual reads
        COMPILER_LDS_FENCE();

        float psumr[7] = {0, 0, 0, 0, 0, 0, 0};
        float s2r[4] = {0, 0, 0, 0};

        // ---------------- main loop over M-tiles (wave-local, no barriers) ----------------
#pragma unroll
        for (int mt = 0; mt < 3; ++mt) {
            if (mt >= mtiles) break;
            const int rbase = mt * 16;
            const int rb = row_base + rbase;

            // L1: A-frag from X (swizzled), eager per-nt consume
            const int arow = rb + m;
            const int slot = qt ^ (arow & 3) ^ ((arow >> 2) & 3);
            short8v a1 = *(const short8v*)(reinterpret_cast<const char*>(X) + arow * 64 + slot * 16);

            const int g16 = (((rb >> 2) + qt) & 3) << 4;   // swizzle part of residual rows
            const char* Xrb = reinterpret_cast<const char*>(X) + (rb + qt * 4) * 64;
#pragma unroll
            for (int nt = 0; nt < 4; ++nt) {
                float4v C1 = __builtin_amdgcn_mfma_f32_16x16x32_bf16(
                    a1, B1g[nt], (float4v){0.f, 0.f, 0.f, 0.f}, 0, 0, 0);
                const int col = nt * 16 + m;
                float vz0 = 0.f, vz1 = 0.f, vz2 = 0.f, vz3 = 0.f;
                if (col < 50) {
                    const int off = rofb[nt] ^ g16;
                    float x0 = bf2f(*(const u16*)(Xrb +   0 + (off ^  0)));
                    float x1 = bf2f(*(const u16*)(Xrb +  64 + (off ^ 16)));
                    float x2_ = bf2f(*(const u16*)(Xrb + 128 + (off ^ 32)));
                    float x3 = bf2f(*(const u16*)(Xrb + 192 + (off ^ 48)));
                    const int lr0 = rbase + qt * 4;
                    // zero pad rows at the source: exact, reused by s2r AND staging
                    vz0 = (lr0 + 0 < vlimit) ? (fast_tanh(C1[0] + b1v[nt]) + x0) : 0.f;
                    vz1 = (lr0 + 1 < vlimit) ? (fast_tanh(C1[1] + b1v[nt]) + x1) : 0.f;
                    vz2 = (lr0 + 2 < vlimit) ? (fast_tanh(C1[2] + b1v[nt]) + x2_) : 0.f;
                    vz3 = (lr0 + 3 < vlimit) ? (fast_tanh(C1[3] + b1v[nt]) + x3) : 0.f;
                }
                s2r[nt] += vz0 + vz1 + vz2 + vz3;
                // stage x2 into row-major tile: row = qt*4+r, col = k index
                u16* q = X2w + (qt * 4) * X2STR + col;
                q[0 * X2STR] = f2bf(vz0);
                q[1 * X2STR] = f2bf(vz1);
                q[2 * X2STR] = f2bf(vz2);
                q[3 * X2STR] = f2bf(vz3);
            }
            // order X2 staging writes before A2 gather reads
            COMPILER_LDS_FENCE();

            // L2: A2 frags via 4x ds_read_b64 (row m, k contiguous)
            short8v a2[2];
#pragma unroll
            for (int kt = 0; kt < 2; ++kt) {
                const u16* g = X2w + m * X2STR + kt * 32 + qt * 8;
                short4v lo = *(const short4v*)(g);
                short4v hi = *(const short4v*)(g + 4);
                a2[kt] = __builtin_shufflevector(lo, hi, 0, 1, 2, 3, 4, 5, 6, 7);
            }
#pragma unroll
            for (int nt = 0; nt < 7; ++nt) {
                // B2 fragments from LDS (ds_read_b128)
                short8v bk0 = *(const short8v*)(B2Ll + (0 * 7 + nt) * 512);
                short8v bk1 = *(const short8v*)(B2Ll + (1 * 7 + nt) * 512);
                float4v C2 = __builtin_amdgcn_mfma_f32_16x16x32_bf16(
                    a2[0], bk0, (float4v){0.f, 0.f, 0.f, 0.f}, 0, 0, 0);
                C2 = __builtin_amdgcn_mfma_f32_16x16x32_bf16(a2[1], bk1, C2, 0, 0, 0);
                // unconditional: pad rows give tanh(b2) (corrected at merge),
                // pad cols give tanh(0)=0 (B2/b2v zero-padded).
#pragma unroll
                for (int r = 0; r < 4; ++r)
                    psumr[nt] += fast_tanh(C2[r] + b2v[nt]);
            }
        }

        // ---------------- cross-quarter reduce, single-barrier merge (ping-pong) ----------------
#pragma unroll
        for (int nt = 0; nt < 7; ++nt) {
            float v = psumr[nt];
            v += __shfl_xor(v, 16);
            v += __shfl_xor(v, 32);
            if (lane < 16) psum[par][wave][nt * 16 + lane] = v - corr[nt];
        }
#pragma unroll
        for (int nt = 0; nt < 4; ++nt) {
            float v = s2r[nt];
            v += __shfl_xor(v, 16);
            v += __shfl_xor(v, 32);
            if (lane < 16) s2w[par][wave][nt * 16 + lane] = v;
        }
        __syncthreads();
        // Safe with ONE barrier: atom ai+2 reuses parity par only after barrier(ai+1).
        if (tid < 100) {
            float ps = psum[par][0][tid] + psum[par][1][tid] + psum[par][2][tid] + psum[par][3][tid];
            const int cm = (tid < 50) ? tid : (tid - 50);
            float s2 = s2w[par][0][cm] + s2w[par][1][cm] + s2w[par][2][cm] + s2w[par][3][cm];
            out_res[b * 100 + tid] = (ps + s2) * (0.2f / 138.0f);
        }
    }
}

extern "C" void kernel_launch(void* const* d_in, const int* in_sizes, int n_in,
                              void* d_out, int out_size, void* d_ws, size_t ws_size,
                              hipStream_t stream) {
    const float* coord  = (const float*)d_in[0];
    const int*   atype  = (const int*)d_in[1];
    const int*   nlist  = (const int*)d_in[2];
    const float* mean   = (const float*)d_in[3];
    const float* stddev = (const float*)d_in[4];
    const float* w0 = (const float*)d_in[5];
    const float* b0 = (const float*)d_in[6];
    const float* w1 = (const float*)d_in[7];
    const float* b1 = (const float*)d_in[8];
    const float* w2 = (const float*)d_in[9];
    const float* b2 = (const float*)d_in[10];

    __hip_bfloat16* wsbf = (__hip_bfloat16*)d_ws;
    const float* TB2 = reinterpret_cast<const float*>(reinterpret_cast<char*>(d_ws) + 36864);
    float* out_res = (float*)d_out;                 // [2][4096][100]
    float* out_sw  = out_res + NF * NLOC * 100;     // [2][4096][138]

    hipLaunchKernelGGL(prep_weights, dim3(72), dim3(256), 0, stream, w1, w2, b2, wsbf);
    hipLaunchKernelGGL(descr_mfma, dim3((NF * NLOC) / ATOMS_PER_BLOCK), dim3(256), 0, stream,
                       coord, atype, nlist, mean, stddev, w0, b0, b1, b2,
                       wsbf /*B1f*/, wsbf + 4096 /*B2f*/, TB2, out_res, out_sw);
}

// Round 16
// 107.585 us; speedup vs baseline: 1.0632x; 1.0632x over previous
//
#include <hip/hip_runtime.h>
#include <hip/hip_bf16.h>

typedef unsigned short u16;
typedef __attribute__((ext_vector_type(4))) short short4v;
typedef __attribute__((ext_vector_type(8))) short short8v;
typedef __attribute__((ext_vector_type(4))) float float4v;

#define NF 2
#define NLOC 4096
#define NALL 8192
#define NNEI_ 138
#define ATOMS_PER_BLOCK 4
#define X2STR 76   // u16 stride of X2 rows: 152 B -> b64-aligned, ~2-way banks both sides

// Compiler-only ordering fence (strict-aliasing write->read on LDS).
#define COMPILER_LDS_FENCE() asm volatile("" ::: "memory")

__device__ __forceinline__ float fast_tanh(float a) {
#if __has_builtin(__builtin_amdgcn_exp2f) && __has_builtin(__builtin_amdgcn_rcpf)
    float t = __builtin_amdgcn_exp2f(a * 2.885390081777927f);  // exp(2a)
    return 1.0f - 2.0f * __builtin_amdgcn_rcpf(t + 1.0f);
#else
    float t = exp2f(a * 2.885390081777927f);
    return 1.0f - 2.0f / (t + 1.0f);
#endif
}

__device__ __forceinline__ u16 f2bf(float x) {
    __hip_bfloat16 h = __float2bfloat16(x);
    return *reinterpret_cast<u16*>(&h);
}

__device__ __forceinline__ float bf2f(u16 b) {
    union { unsigned int u; float f; } c;
    c.u = ((unsigned int)b) << 16;
    return c.f;
}

// Pack weights into MFMA B-fragment order (bf16), zero-padded.
// B1: [2 types][4 ntiles][64 lanes][8 elems]   (K=25->32, N=50->64)
// B2: [2 types][2 ktiles][7 ntiles][64][8]     (K=50->64, N=100->112)
__global__ void prep_weights(const float* __restrict__ w1, const float* __restrict__ w2,
                             __hip_bfloat16* __restrict__ wsbf) {
    int i = threadIdx.x + blockIdx.x * blockDim.x;
    if (i < 4096) {
        int e = i & 7, lane = (i >> 3) & 63, nt = (i >> 9) & 3, t = i >> 11;
        int k = (lane >> 4) * 8 + e, j = nt * 16 + (lane & 15);
        float v = (k < 25 && j < 50) ? w1[t * 1250 + k * 50 + j] : 0.0f;
        wsbf[i] = __float2bfloat16(v);
    } else if (i < 4096 + 14336) {
        int j2 = i - 4096;
        int e = j2 & 7, lane = (j2 >> 3) & 63;
        int q = j2 >> 9;
        int nt = q % 7, kt = (q / 7) & 1, t = q / 14;
        int k = kt * 32 + (lane >> 4) * 8 + e, j = nt * 16 + (lane & 15);
        float v = (k < 50 && j < 100) ? w2[t * 5000 + k * 100 + j] : 0.0f;
        wsbf[4096 + j2] = __float2bfloat16(v);
    }
}

// Block = ATOMS_PER_BLOCK atoms, processed sequentially.
// Rows: 0-47 = type0 neighbors 0-45 (+2 pad), wave 0.
//       48-143 = type1 neighbors 46-137 (+4 pad), waves 1-3 (32 rows each).
// Phase-A global loads for atom ai+1 are PREFETCHED during atom ai's M-loop:
// the nlist->coord dependent chain (~400-900cy L2) otherwise stalls all 4
// waves simultaneously right after each merge barrier.
__global__ __launch_bounds__(256, 3) void descr_mfma(
    const float* __restrict__ coord, const int* __restrict__ atype,
    const int* __restrict__ nlist, const float* __restrict__ mean,
    const float* __restrict__ stddev,
    const float* __restrict__ w0, const float* __restrict__ b0,
    const float* __restrict__ b1, const float* __restrict__ b2,
    const __hip_bfloat16* __restrict__ B1f, const __hip_bfloat16* __restrict__ B2f,
    float* __restrict__ out_res, float* __restrict__ out_sw)
{
    // X: layer-0 activations, row-major 64B rows, 16B-slot swizzle
    //    slot(row, sl) = sl ^ (row&3) ^ ((row>>2)&3)
    __shared__ __align__(16) u16 X[144 * 32];               // 9216 B
    // X2: per-wave current-tile x2, ROW-major [16 rows][X2STR]
    __shared__ __align__(16) u16 X2[4 * 16 * X2STR];        // 9728 B
    __shared__ __align__(16) u16 B2L[2 * 7168];             // 28672 B, full B2 pack (both types)
    __shared__ float psum[2][4][112];                       // 3584 B (ping-pong by atom parity)
    __shared__ float s2w[2][4][64];                         // 2048 B

    const int tid = threadIdx.x, wave = tid >> 6, lane = tid & 63;
    const int t = wave ? 1 : 0;
    const int row_base = wave ? (48 + 32 * (wave - 1)) : 0;
    const int n_rows = wave ? 32 : 48;
    const int mtiles = wave ? 2 : 3;
    const int vlimit = (wave == 0) ? 46 : ((wave == 3) ? 28 : 32);
    const int m = lane & 15, qt = lane >> 4;
    const int nslot = wave ? (row_base + lane - 2) : lane;   // neighbor slot (loop-invariant)
    u16* const X2w = X2 + wave * (16 * X2STR);

    // per-atom prefetched phase-A inputs
    struct PrefT { int jn; int aty; float cx, cy, cz, ncx, ncy, ncz, mn, sd; };
    PrefT P;
    auto do_prefetch = [&](int ai2, PrefT& Q) {
        const int bb = blockIdx.x * ATOMS_PER_BLOCK + ai2;
        const int ff = bb >> 12, ill = bb & 4095;
        Q.aty = atype[ff * NALL + ill];                       // wave-uniform -> s_load
        Q.cx = coord[(ff * NALL + ill) * 3 + 0];
        Q.cy = coord[(ff * NALL + ill) * 3 + 1];
        Q.cz = coord[(ff * NALL + ill) * 3 + 2];
        Q.jn = -1;
        if (lane < vlimit) {
            Q.jn = nlist[bb * NNEI_ + nslot];
            const int jj = (Q.jn >= 0) ? Q.jn : 0;
            Q.ncx = coord[(ff * NALL + jj) * 3 + 0];
            Q.ncy = coord[(ff * NALL + jj) * 3 + 1];
            Q.ncz = coord[(ff * NALL + jj) * 3 + 2];
            Q.mn = mean[Q.aty * NNEI_ + nslot];
            Q.sd = stddev[Q.aty * NNEI_ + nslot];
        }
    };

    // prologue prefetch for atom 0 (latency hides under B2L staging + barrier)
    do_prefetch(0, P);

    // ---------------- stage full B2 pack into LDS once per block ----------------
    {
        const uint4* src = reinterpret_cast<const uint4*>(B2f);   // 28672 B = 1792 uint4
        uint4* dst = reinterpret_cast<uint4*>(B2L);
#pragma unroll
        for (int i = 0; i < 7; ++i) {
            int idx = tid + i * 256;
            dst[idx] = src[idx];
        }
    }
    __syncthreads();

    // ---------------- per-type constants & B1 fragments (hoisted over atoms) ----------------
    float b1v[4], b2v[7];
    int rofb[4];   // residual in-row byte offset: (slot<<4)|obyte  (pre-swizzle)
#pragma unroll
    for (int nt = 0; nt < 4; ++nt) {
        int col = nt * 16 + m;
        b1v[nt] = (col < 50) ? b1[t * 50 + col] : 0.0f;
        int cm = (col < 25) ? col : ((col < 50) ? (col - 25) : 0);
        rofb[nt] = ((cm >> 3) << 4) | ((cm & 7) * 2);
    }
#pragma unroll
    for (int nt = 0; nt < 7; ++nt) {
        int col = nt * 16 + m;
        b2v[nt] = (col < 100) ? b2[t * 100 + col] : 0.0f;
    }
    short8v B1g[4];
#pragma unroll
    for (int nt = 0; nt < 4; ++nt)
        B1g[nt] = *(const short8v*)(B1f + ((t * 4 + nt) * 64 + lane) * 8);
    // B2 fragments are read from LDS per use (ds_read_b128).
    const u16* const B2Ll = B2L + t * 7168 + lane * 8;

    const float* w0t = w0 + t * 25;
    const float* b0t = b0 + t * 25;

#pragma unroll 1
    for (int ai = 0; ai < ATOMS_PER_BLOCK; ++ai) {
        const int b = blockIdx.x * ATOMS_PER_BLOCK + ai;
        const int par = ai & 1;

        // ---------------- phase A: s, sw, X staging (from prefetched inputs) ----------------
        {
            float s = 0.0f;
            const int row = row_base + lane;
            if (lane < vlimit) {
                float sw = 0.0f, env = 0.0f;
                if (P.jn >= 0) {
                    float dx = P.ncx - P.cx;
                    float dy = P.ncy - P.cy;
                    float dz = P.ncz - P.cz;
                    float len = sqrtf(dx * dx + dy * dy + dz * dz);
                    float uu = (len - 0.5f) * (1.0f / 5.5f);
                    float vv = uu * uu * uu * (uu * (-6.0f * uu + 15.0f) - 10.0f) + 1.0f;
                    sw = (len <= 0.5f) ? 1.0f : ((len >= 6.0f) ? 0.0f : vv);
                    env = sw / len;
                }
                out_sw[b * NNEI_ + nslot] = sw;
                s = (env - P.mn) / P.sd;
            }
            if (lane < n_rows) {
                unsigned int xp[16];
#pragma unroll
                for (int kk = 0; kk < 13; ++kk) {
                    float v0 = fast_tanh(s * w0t[2 * kk] + b0t[2 * kk]);
                    float v1 = (2 * kk + 1 < 25) ? fast_tanh(s * w0t[2 * kk + 1] + b0t[2 * kk + 1]) : 0.0f;
                    xp[kk] = (unsigned int)f2bf(v0) | ((unsigned int)f2bf(v1) << 16);
                }
                xp[13] = 0; xp[14] = 0; xp[15] = 0;
#pragma unroll
                for (int sl = 0; sl < 4; ++sl) {
                    int slot = sl ^ (row & 3) ^ ((row >> 2) & 3);
                    uint4 v = make_uint4(xp[4 * sl], xp[4 * sl + 1], xp[4 * sl + 2], xp[4 * sl + 3]);
                    *reinterpret_cast<uint4*>(reinterpret_cast<char*>(X) + row * 64 + slot * 16) = v;
                }
            }
        }
        // order phase-A X stores before a1/residual reads
        COMPILER_LDS_FENCE();

        // issue next atom's phase-A load chain; ~2 M-tiles of compute cover it
        if (ai + 1 < ATOMS_PER_BLOCK) do_prefetch(ai + 1, P);

        float psumr[7] = {0, 0, 0, 0, 0, 0, 0};
        float s2r[4] = {0, 0, 0, 0};

        // ---------------- main loop over M-tiles (wave-local, no barriers) ----------------
#pragma unroll
        for (int mt = 0; mt < 3; ++mt) {
            if (mt >= mtiles) break;
            const int rbase = mt * 16;
            const int rb = row_base + rbase;

            // L1: A-frag from X (swizzled), eager per-nt consume
            const int arow = rb + m;
            const int slot = qt ^ (arow & 3) ^ ((arow >> 2) & 3);
            short8v a1 = *(const short8v*)(reinterpret_cast<const char*>(X) + arow * 64 + slot * 16);

            const int g16 = (((rb >> 2) + qt) & 3) << 4;   // swizzle part of residual rows
            const char* Xrb = reinterpret_cast<const char*>(X) + (rb + qt * 4) * 64;
#pragma unroll
            for (int nt = 0; nt < 4; ++nt) {
                float4v C1 = __builtin_amdgcn_mfma_f32_16x16x32_bf16(
                    a1, B1g[nt], (float4v){0.f, 0.f, 0.f, 0.f}, 0, 0, 0);
                const int col = nt * 16 + m;
                float v0 = 0.f, v1 = 0.f, v2 = 0.f, v3 = 0.f;
                if (col < 50) {
                    const int off = rofb[nt] ^ g16;
                    float x0 = bf2f(*(const u16*)(Xrb +   0 + (off ^  0)));
                    float x1 = bf2f(*(const u16*)(Xrb +  64 + (off ^ 16)));
                    float x2_ = bf2f(*(const u16*)(Xrb + 128 + (off ^ 32)));
                    float x3 = bf2f(*(const u16*)(Xrb + 192 + (off ^ 48)));
                    v0 = fast_tanh(C1[0] + b1v[nt]) + x0;
                    v1 = fast_tanh(C1[1] + b1v[nt]) + x1;
                    v2 = fast_tanh(C1[2] + b1v[nt]) + x2_;
                    v3 = fast_tanh(C1[3] + b1v[nt]) + x3;
                }
                const int lr0 = rbase + qt * 4;
                s2r[nt] += ((lr0 + 0 < vlimit) ? v0 : 0.f) + ((lr0 + 1 < vlimit) ? v1 : 0.f) +
                           ((lr0 + 2 < vlimit) ? v2 : 0.f) + ((lr0 + 3 < vlimit) ? v3 : 0.f);
                // stage x2 into row-major tile: row = qt*4+r, col = k index
                u16* q = X2w + (qt * 4) * X2STR + col;
                q[0 * X2STR] = f2bf(v0);
                q[1 * X2STR] = f2bf(v1);
                q[2 * X2STR] = f2bf(v2);
                q[3 * X2STR] = f2bf(v3);
            }
            // order X2 staging writes before A2 gather reads
            COMPILER_LDS_FENCE();

            // L2: A2 frags via 4x ds_read_b64 (row m, k contiguous)
            short8v a2[2];
#pragma unroll
            for (int kt = 0; kt < 2; ++kt) {
                const u16* g = X2w + m * X2STR + kt * 32 + qt * 8;
                short4v lo = *(const short4v*)(g);
                short4v hi = *(const short4v*)(g + 4);
                a2[kt] = __builtin_shufflevector(lo, hi, 0, 1, 2, 3, 4, 5, 6, 7);
            }
#pragma unroll
            for (int nt = 0; nt < 7; ++nt) {
                // B2 fragments from LDS (ds_read_b128)
                short8v bk0 = *(const short8v*)(B2Ll + (0 * 7 + nt) * 512);
                short8v bk1 = *(const short8v*)(B2Ll + (1 * 7 + nt) * 512);
                float4v C2 = __builtin_amdgcn_mfma_f32_16x16x32_bf16(
                    a2[0], bk0, (float4v){0.f, 0.f, 0.f, 0.f}, 0, 0, 0);
                C2 = __builtin_amdgcn_mfma_f32_16x16x32_bf16(a2[1], bk1, C2, 0, 0, 0);
                const int col = nt * 16 + m;
                const int lr0 = rbase + qt * 4;
#pragma unroll
                for (int r = 0; r < 4; ++r) {
                    float g = fast_tanh(C2[r] + b2v[nt]);
                    psumr[nt] += (col < 100 && (lr0 + r) < vlimit) ? g : 0.f;
                }
            }
        }

        // ---------------- cross-quarter reduce, single-barrier merge (ping-pong) ----------------
#pragma unroll
        for (int nt = 0; nt < 7; ++nt) {
            float v = psumr[nt];
            v += __shfl_xor(v, 16);
            v += __shfl_xor(v, 32);
            if (lane < 16) psum[par][wave][nt * 16 + lane] = v;
        }
#pragma unroll
        for (int nt = 0; nt < 4; ++nt) {
            float v = s2r[nt];
            v += __shfl_xor(v, 16);
            v += __shfl_xor(v, 32);
            if (lane < 16) s2w[par][wave][nt * 16 + lane] = v;
        }
        __syncthreads();
        // Safe with ONE barrier: atom ai+2 reuses parity par only after barrier(ai+1).
        if (tid < 100) {
            float ps = psum[par][0][tid] + psum[par][1][tid] + psum[par][2][tid] + psum[par][3][tid];
            const int cm = (tid < 50) ? tid : (tid - 50);
            float s2 = s2w[par][0][cm] + s2w[par][1][cm] + s2w[par][2][cm] + s2w[par][3][cm];
            out_res[b * 100 + tid] = (ps + s2) * (0.2f / 138.0f);
        }
    }
}

extern "C" void kernel_launch(void* const* d_in, const int* in_sizes, int n_in,
                              void* d_out, int out_size, void* d_ws, size_t ws_size,
                              hipStream_t stream) {
    const float* coord  = (const float*)d_in[0];
    const int*   atype  = (const int*)d_in[1];
    const int*   nlist  = (const int*)d_in[2];
    const float* mean   = (const float*)d_in[3];
    const float* stddev = (const float*)d_in[4];
    const float* w0 = (const float*)d_in[5];
    const float* b0 = (const float*)d_in[6];
    const float* w1 = (const float*)d_in[7];
    const float* b1 = (const float*)d_in[8];
    const float* w2 = (const float*)d_in[9];
    const float* b2 = (const float*)d_in[10];

    __hip_bfloat16* wsbf = (__hip_bfloat16*)d_ws;
    float* out_res = (float*)d_out;                 // [2][4096][100]
    float* out_sw  = out_res + NF * NLOC * 100;     // [2][4096][138]

    hipLaunchKernelGGL(prep_weights, dim3(72), dim3(256), 0, stream, w1, w2, wsbf);
    hipLaunchKernelGGL(descr_mfma, dim3((NF * NLOC) / ATOMS_PER_BLOCK), dim3(256), 0, stream,
                       coord, atype, nlist, mean, stddev, w0, b0, b1, b2,
                       wsbf /*B1f*/, wsbf + 4096 /*B2f*/, out_res, out_sw);
}